// Round 1
// baseline (6759.597 us; speedup 1.0000x reference)
//
#include <hip/hip_runtime.h>
#include <stdint.h>

// Persistent-kernel pipelined LSTM for MI355X.
// - 128 WGs x 256 thr: WG 0..63 = layer0 (units 16*wg..), WG 64..127 = layer1.
// - Stage s: layer0 computes step t=s, layer1 computes step t=s-1 (pipeline).
// - Gate GEMM 64x48 per WG (i,g,o only - f gate is dead code), MFMA 16x16x32 f16,
//   4-wave K-split, LDS reduce, fp32 elementwise + fp32 cell state.
// - Grid barrier: ws-resident counter/flag, agent-scope atomics (cross-XCD safe).

#define T_STEPS 256
#define HDIM    1024
#define NB      64
#define INDIM   512
#define NWG     128
#define TPB     256

typedef _Float16 f16;
typedef __attribute__((ext_vector_type(8))) _Float16 f16x8;
typedef __attribute__((ext_vector_type(4))) float    f32x4;

// ws byte offsets (all 16B aligned)
#define BAR_OFF 0
#define WL0_OFF 512                       // f16 [3072][1536]  packed [i|g|o] x [Wx0|Wh0]
#define WL1_OFF 9437696                   // f16 [3072][2048]  packed [i|g|o] x [Wx1|Wh1]
#define XB_OFF  22020608                  // f16 [256][64][512]   x, time-major
#define H0_OFF  38797824                  // f16 [257][64][1024]  layer0 h, slot t+1 = h0_t
#define H1_OFF  72483328                  // f16 [2][64][1024]    layer1 h ring
#define C0_OFF  72745472                  // f32 [64][1024]
#define C1_OFF  73007616                  // f32 [64][1024]

__device__ __forceinline__ float sigm(float x)     { return 1.0f / (1.0f + __expf(-x)); }
__device__ __forceinline__ float tanhfast(float x) { float e = __expf(2.0f * x); return 1.0f - 2.0f / (e + 1.0f); }

__device__ __forceinline__ void gbar(int* cnt, int* flag, int ep) {
  __syncthreads();
  if (threadIdx.x == 0) {
    int old = __hip_atomic_fetch_add(cnt, 1, __ATOMIC_ACQ_REL, __HIP_MEMORY_SCOPE_AGENT);
    if (old == ep * NWG - 1) {
      __hip_atomic_store(flag, ep, __ATOMIC_RELEASE, __HIP_MEMORY_SCOPE_AGENT);
    } else {
      while (__hip_atomic_load(flag, __ATOMIC_RELAXED, __HIP_MEMORY_SCOPE_AGENT) < ep)
        __builtin_amdgcn_s_sleep(1);
      (void)__hip_atomic_load(flag, __ATOMIC_ACQUIRE, __HIP_MEMORY_SCOPE_AGENT);
    }
  }
  __syncthreads();
}

__global__ __launch_bounds__(TPB) void lstm_pers(
    const float* __restrict__ x,
    const float* __restrict__ Wx0, const float* __restrict__ Wh0,
    const float* __restrict__ b0,  const float* __restrict__ Wc0,
    const float* __restrict__ Wx1, const float* __restrict__ Wh1,
    const float* __restrict__ b1,  const float* __restrict__ Wc1,
    float* __restrict__ out, char* __restrict__ ws)
{
  int* bcnt  = (int*)(ws + BAR_OFF);
  int* bflag = (int*)(ws + BAR_OFF + 128);
  f16* WL0 = (f16*)(ws + WL0_OFF);
  f16* WL1 = (f16*)(ws + WL1_OFF);
  f16* XB  = (f16*)(ws + XB_OFF);
  f16* H0  = (f16*)(ws + H0_OFF);
  f16* H1  = (f16*)(ws + H1_OFF);
  float* C0 = (float*)(ws + C0_OFF);
  float* C1 = (float*)(ws + C1_OFF);

  __shared__ float lds[4][64][49];   // [wave][m][ncol], +1 pad breaks bank conflicts

  const int tid  = threadIdx.x;
  const int wg   = blockIdx.x;
  const int gtid = wg * TPB + tid;
  const int GSZ  = NWG * TPB;

  // ---------------- prologue: pack weights & x into fp16 layouts ----------------
  // WL row r: unit-group grp=r/48, within-block w=r%48, gate=w>>4 (0=i,1=g,2=o), j=w&15
  for (int idx = gtid; idx < 3072 * 1536; idx += GSZ) {
    int r = idx / 1536, c = idx - r * 1536;
    int grp = r / 48, w = r - grp * 48;
    int gate = w >> 4, j = w & 15;
    int R = grp * 16 + j + (gate == 1 ? 2048 : (gate == 2 ? 3072 : 0));
    float v = (c < INDIM) ? Wx0[R * INDIM + c] : Wh0[R * HDIM + (c - INDIM)];
    WL0[idx] = (f16)v;
  }
  for (int idx = gtid; idx < 3072 * 2048; idx += GSZ) {
    int r = idx >> 11, c = idx & 2047;
    int grp = r / 48, w = r - grp * 48;
    int gate = w >> 4, j = w & 15;
    int R = grp * 16 + j + (gate == 1 ? 2048 : (gate == 2 ? 3072 : 0));
    float v = (c < HDIM) ? Wx1[R * HDIM + c] : Wh1[R * HDIM + (c - HDIM)];
    WL1[idx] = (f16)v;
  }
  for (int idx = gtid; idx < T_STEPS * NB * INDIM; idx += GSZ) {
    int t = idx >> 15, rem = idx & 32767;
    int n = rem >> 9, i = rem & 511;
    XB[idx] = (f16)x[(size_t)n * (T_STEPS * INDIM) + t * INDIM + i];
  }

  int ep = 1;
  gbar(bcnt, bflag, ep);

  // ---------------- persistent stage loop ----------------
  const int layer = wg >> 6;
  const int ug    = wg & 63;          // unit group: units [16*ug, 16*ug+16)
  const int lane  = tid & 63;
  const int wv    = tid >> 6;
  const int quad  = lane >> 4;
  const int lr    = lane & 15;

  const int K   = layer ? 2048 : 1536;
  const int Kq  = K >> 2;             // per-wave K slice
  const f16* Wm = layer ? WL1 : WL0;
  const float* bb = layer ? b1 : b0;
  const float* wc = layer ? Wc1 : Wc0;
  float* cst = layer ? C1 : C0;

  // B fragment row pointers (B[k][n] = W[n][k], 8 consecutive k = 16B load)
  const f16* wrow0 = Wm + (size_t)(ug * 48 +  0 + lr) * K + wv * Kq + quad * 8;
  const f16* wrow1 = Wm + (size_t)(ug * 48 + 16 + lr) * K + wv * Kq + quad * 8;
  const f16* wrow2 = Wm + (size_t)(ug * 48 + 32 + lr) * K + wv * Kq + quad * 8;

  for (int s = 0; s <= T_STEPS; ++s) {
    const bool active = layer ? (s >= 1) : (s < T_STEPS);
    if (active) {
      const int t = layer ? (s - 1) : s;

      // A = [x_t | h0_{t-1}] (layer0)  or  [h0_t | h1_{t-1}] (layer1)
      const f16 *s0p, *s1p; int s0len, s0sh, s1sh;
      if (layer == 0) {
        s0p = XB + (size_t)t * NB * INDIM; s0len = INDIM; s0sh = 9;
        s1p = H0 + (size_t)s * NB * HDIM;  s1sh = 10;
      } else {
        s0p = H0 + (size_t)s * NB * HDIM;  s0len = HDIM;  s0sh = 10;
        s1p = H1 + (size_t)((t + 1) & 1) * NB * HDIM; s1sh = 10;
      }

      f32x4 acc[4][3];
      for (int mt = 0; mt < 4; ++mt)
        for (int nt = 0; nt < 3; ++nt)
          acc[mt][nt] = (f32x4){0.f, 0.f, 0.f, 0.f};

      // per-wave K range [wv*Kq, wv*Kq+Kq), split at segment boundary s0len
      int kend0 = s0len - wv * Kq;
      if (kend0 < 0) kend0 = 0;
      if (kend0 > Kq) kend0 = Kq;

      auto run_seg = [&](const f16* abase, int sh, int kk0, int kk1) {
        const f16* a0p = abase + ((0 * 16 + lr) << sh) + quad * 8;
        const f16* a1p = abase + ((1 * 16 + lr) << sh) + quad * 8;
        const f16* a2p = abase + ((2 * 16 + lr) << sh) + quad * 8;
        const f16* a3p = abase + ((3 * 16 + lr) << sh) + quad * 8;
        #pragma unroll 2
        for (int kk = kk0; kk < kk1; kk += 32) {
          f16x8 a0 = *(const f16x8*)(a0p + kk);
          f16x8 a1 = *(const f16x8*)(a1p + kk);
          f16x8 a2 = *(const f16x8*)(a2p + kk);
          f16x8 a3 = *(const f16x8*)(a3p + kk);
          f16x8 q0 = *(const f16x8*)(wrow0 + kk);
          f16x8 q1 = *(const f16x8*)(wrow1 + kk);
          f16x8 q2 = *(const f16x8*)(wrow2 + kk);
          acc[0][0] = __builtin_amdgcn_mfma_f32_16x16x32_f16(a0, q0, acc[0][0], 0, 0, 0);
          acc[0][1] = __builtin_amdgcn_mfma_f32_16x16x32_f16(a0, q1, acc[0][1], 0, 0, 0);
          acc[0][2] = __builtin_amdgcn_mfma_f32_16x16x32_f16(a0, q2, acc[0][2], 0, 0, 0);
          acc[1][0] = __builtin_amdgcn_mfma_f32_16x16x32_f16(a1, q0, acc[1][0], 0, 0, 0);
          acc[1][1] = __builtin_amdgcn_mfma_f32_16x16x32_f16(a1, q1, acc[1][1], 0, 0, 0);
          acc[1][2] = __builtin_amdgcn_mfma_f32_16x16x32_f16(a1, q2, acc[1][2], 0, 0, 0);
          acc[2][0] = __builtin_amdgcn_mfma_f32_16x16x32_f16(a2, q0, acc[2][0], 0, 0, 0);
          acc[2][1] = __builtin_amdgcn_mfma_f32_16x16x32_f16(a2, q1, acc[2][1], 0, 0, 0);
          acc[2][2] = __builtin_amdgcn_mfma_f32_16x16x32_f16(a2, q2, acc[2][2], 0, 0, 0);
          acc[3][0] = __builtin_amdgcn_mfma_f32_16x16x32_f16(a3, q0, acc[3][0], 0, 0, 0);
          acc[3][1] = __builtin_amdgcn_mfma_f32_16x16x32_f16(a3, q1, acc[3][1], 0, 0, 0);
          acc[3][2] = __builtin_amdgcn_mfma_f32_16x16x32_f16(a3, q2, acc[3][2], 0, 0, 0);
        }
      };
      // segment 0: A offset = wv*Kq + kk ; segment 1: A offset = wv*Kq + kk - s0len
      if (kend0 > 0) run_seg(s0p + wv * Kq,         s0sh, 0,     kend0);
      if (kend0 < Kq) run_seg(s1p + wv * Kq - s0len, s1sh, kend0, Kq);

      // cross-wave partial reduce through LDS
      for (int mt = 0; mt < 4; ++mt)
        for (int nt = 0; nt < 3; ++nt)
          for (int r = 0; r < 4; ++r)
            lds[wv][mt * 16 + quad * 4 + r][nt * 16 + lr] = acc[mt][nt][r];
      __syncthreads();

      // elementwise epilogue: 1024 outputs (m in [0,64), j in [0,16)), 4 per thread
      for (int rep = 0; rep < 4; ++rep) {
        int idx = rep * TPB + tid;
        int m = idx & 63, j = idx >> 6;
        float gi = lds[0][m][j]      + lds[1][m][j]      + lds[2][m][j]      + lds[3][m][j];
        float gg = lds[0][m][16 + j] + lds[1][m][16 + j] + lds[2][m][16 + j] + lds[3][m][16 + j];
        float go = lds[0][m][32 + j] + lds[1][m][32 + j] + lds[2][m][32 + j] + lds[3][m][32 + j];
        int u = ug * 16 + j;
        float cold = cst[m * HDIM + u];
        float iv = sigm(gi + bb[u] + wc[u] * cold);               // i: Wc[0]
        float gv = tanhfast(gg + bb[2048 + u]);                   // g
        float ov = sigm(go + bb[3072 + u] + wc[2048 + u] * cold); // o: Wc[2]
        float cn = gv * (cold + iv);     // faithful: ct = g*c + i*g
        float hv = ov * tanhfast(cold);  // faithful: uses OLD cell state
        cst[m * HDIM + u] = cn;
        if (layer == 0) {
          H0[(size_t)(s + 1) * NB * HDIM + m * HDIM + u] = (f16)hv;
        } else {
          H1[(size_t)(t & 1) * NB * HDIM + m * HDIM + u] = (f16)hv;
          out[(size_t)m * (T_STEPS * HDIM) + (size_t)t * HDIM + u] = hv;
          if (t == T_STEPS - 1) {
            out[(size_t)NB * T_STEPS * HDIM + m * HDIM + u] = hv;               // final h1
            out[(size_t)NB * T_STEPS * HDIM + NB * HDIM + m * HDIM + u] = cn;   // final c1
          }
        }
      }
    }
    gbar(bcnt, bflag, ++ep);   // also provides LDS WAR protection via its syncthreads
  }
}

extern "C" void kernel_launch(void* const* d_in, const int* in_sizes, int n_in,
                              void* d_out, int out_size, void* d_ws, size_t ws_size,
                              hipStream_t stream) {
  const float* x   = (const float*)d_in[0];
  const float* Wx0 = (const float*)d_in[1];
  const float* Wh0 = (const float*)d_in[2];
  const float* b0  = (const float*)d_in[3];
  const float* Wc0 = (const float*)d_in[4];
  const float* Wx1 = (const float*)d_in[5];
  const float* Wh1 = (const float*)d_in[6];
  const float* b1  = (const float*)d_in[7];
  const float* Wc1 = (const float*)d_in[8];
  char* ws = (char*)d_ws;

  // ws is re-poisoned to 0xAA before every timed launch: re-init barrier + state.
  hipMemsetAsync(ws + BAR_OFF, 0, 512, stream);                 // barrier cnt/flag
  hipMemsetAsync(ws + H0_OFF, 0, NB * HDIM * 2, stream);        // h0_{-1} = 0
  hipMemsetAsync(ws + H1_OFF, 0, 2 * NB * HDIM * 2, stream);    // h1 ring = 0
  hipMemsetAsync(ws + C0_OFF, 0, 2 * NB * HDIM * 4, stream);    // c0, c1 = 0 (contiguous)

  hipLaunchKernelGGL(lstm_pers, dim3(NWG), dim3(TPB), 0, stream,
                     x, Wx0, Wh0, b0, Wc0, Wx1, Wh1, b1, Wc1,
                     (float*)d_out, ws);
}

// Round 2
// 6428.082 us; speedup vs baseline: 1.0516x; 1.0516x over previous
//
#include <hip/hip_runtime.h>
#include <stdint.h>

// 4-group pipelined persistent LSTM, MI355X.
// Groups of 64 WGs each (256 total, 1/CU):
//   P0: G0(t) = x_t @ Wx0p^T            (K=512)  -> P0buf ring
//   L0: h0_t  = eps(P0buf + h0_{t-1} @ Wh0p^T)   (K=1024)
//   P1: G1(t) = h0_t @ Wx1p^T           (K=1024) -> P1buf ring
//   L1: h1_t  = eps(P1buf + h1_{t-1} @ Wh1p^T)   (K=1024) -> out
// Pipeline: P0@t=s, L0@t=s-1, P1@t=s-2, L1@t=s-3; 259 stages.
// f-gate is dead code (reference quirk) -> only [i|g|o] = 48 gate rows/WG.
// MFMA 16x16x32 f16, 4-wave K-split, LDS reduce, fp32 state.
// Two-level grid barrier (16 padded sub-counters x16 + master + flag).

#define T_STEPS 256
#define HDIM    1024
#define NB      64
#define INDIM   512
#define NWG     256
#define TPB     256
#define NSTAGES 259

typedef _Float16 f16;
typedef __attribute__((ext_vector_type(8))) _Float16 f16x8;
typedef __attribute__((ext_vector_type(4))) float    f32x4;

// ws byte offsets
#define BAR_OFF 0            // subs: 16 x 256B; master @ +8192; flag @ +8448
#define WX0_OFF 16384        // f16 [3072][512]   packed [i|g|o] Wx0
#define WH0_OFF 3162112      // f16 [3072][1024]  packed Wh0
#define WX1_OFF 9453568      // f16 [3072][1024]  packed Wx1
#define WH1_OFF 15745024     // f16 [3072][1024]  packed Wh1
#define XB_OFF  22036480     // f16 [256][64][512]  x time-major
#define H0_OFF  38813696     // f16 [257][64][1024] slot t = h0_{t-1}
#define H1_OFF  72499200     // f16 [2][64][1024]   ring
#define C0_OFF  72761344     // f32 [64][1024]
#define C1_OFF  73023488     // f32 [64][1024]
#define P0_OFF  73285632     // f32 [2][3072][64]   (transposed: col-major over m)
#define P1_OFF  74858496     // f32 [2][3072][64]

__device__ __forceinline__ float sigm(float x)     { return 1.0f / (1.0f + __expf(-x)); }
__device__ __forceinline__ float tanhfast(float x) { float e = __expf(2.0f * x); return 1.0f - 2.0f / (e + 1.0f); }

__device__ __forceinline__ void gbar2(int* subs, int* master, int* flag, int wg, int ep) {
  __syncthreads();
  if (threadIdx.x == 0) {
    int* sc = subs + (wg & 15) * 64;   // 256B-padded sub-counter lines
    int old = __hip_atomic_fetch_add(sc, 1, __ATOMIC_ACQ_REL, __HIP_MEMORY_SCOPE_AGENT);
    if (old == ep * 16 - 1) {
      int mo = __hip_atomic_fetch_add(master, 1, __ATOMIC_ACQ_REL, __HIP_MEMORY_SCOPE_AGENT);
      if (mo == ep * 16 - 1)
        __hip_atomic_store(flag, ep, __ATOMIC_RELEASE, __HIP_MEMORY_SCOPE_AGENT);
    }
    while (__hip_atomic_load(flag, __ATOMIC_RELAXED, __HIP_MEMORY_SCOPE_AGENT) < ep)
      __builtin_amdgcn_s_sleep(1);
    (void)__hip_atomic_load(flag, __ATOMIC_ACQUIRE, __HIP_MEMORY_SCOPE_AGENT);
  }
  __syncthreads();
}

template<int NIT>
__device__ __forceinline__ void gemm48(const f16* __restrict__ Aw, int ash,
                                       const f16* __restrict__ w0,
                                       const f16* __restrict__ w1,
                                       const f16* __restrict__ w2,
                                       int lr, f32x4 (&acc)[4][3]) {
  const f16* a0 = Aw + ((size_t)(lr +  0) << ash);
  const f16* a1 = Aw + ((size_t)(lr + 16) << ash);
  const f16* a2 = Aw + ((size_t)(lr + 32) << ash);
  const f16* a3 = Aw + ((size_t)(lr + 48) << ash);
#pragma unroll
  for (int it = 0; it < NIT; ++it) {
    const int kk = it * 32;
    f16x8 A0 = *(const f16x8*)(a0 + kk);
    f16x8 A1 = *(const f16x8*)(a1 + kk);
    f16x8 A2 = *(const f16x8*)(a2 + kk);
    f16x8 A3 = *(const f16x8*)(a3 + kk);
    f16x8 B0 = *(const f16x8*)(w0 + kk);
    f16x8 B1 = *(const f16x8*)(w1 + kk);
    f16x8 B2 = *(const f16x8*)(w2 + kk);
    acc[0][0] = __builtin_amdgcn_mfma_f32_16x16x32_f16(A0, B0, acc[0][0], 0, 0, 0);
    acc[0][1] = __builtin_amdgcn_mfma_f32_16x16x32_f16(A0, B1, acc[0][1], 0, 0, 0);
    acc[0][2] = __builtin_amdgcn_mfma_f32_16x16x32_f16(A0, B2, acc[0][2], 0, 0, 0);
    acc[1][0] = __builtin_amdgcn_mfma_f32_16x16x32_f16(A1, B0, acc[1][0], 0, 0, 0);
    acc[1][1] = __builtin_amdgcn_mfma_f32_16x16x32_f16(A1, B1, acc[1][1], 0, 0, 0);
    acc[1][2] = __builtin_amdgcn_mfma_f32_16x16x32_f16(A1, B2, acc[1][2], 0, 0, 0);
    acc[2][0] = __builtin_amdgcn_mfma_f32_16x16x32_f16(A2, B0, acc[2][0], 0, 0, 0);
    acc[2][1] = __builtin_amdgcn_mfma_f32_16x16x32_f16(A2, B1, acc[2][1], 0, 0, 0);
    acc[2][2] = __builtin_amdgcn_mfma_f32_16x16x32_f16(A2, B2, acc[2][2], 0, 0, 0);
    acc[3][0] = __builtin_amdgcn_mfma_f32_16x16x32_f16(A3, B0, acc[3][0], 0, 0, 0);
    acc[3][1] = __builtin_amdgcn_mfma_f32_16x16x32_f16(A3, B1, acc[3][1], 0, 0, 0);
    acc[3][2] = __builtin_amdgcn_mfma_f32_16x16x32_f16(A3, B2, acc[3][2], 0, 0, 0);
  }
}

__global__ __launch_bounds__(TPB) void lstm_pers(
    const float* __restrict__ x,
    const float* __restrict__ Wx0, const float* __restrict__ Wh0,
    const float* __restrict__ b0,  const float* __restrict__ Wc0,
    const float* __restrict__ Wx1, const float* __restrict__ Wh1,
    const float* __restrict__ b1,  const float* __restrict__ Wc1,
    float* __restrict__ out, char* __restrict__ ws)
{
  int* subs   = (int*)(ws + BAR_OFF);
  int* master = (int*)(ws + BAR_OFF + 8192);
  int* flag   = (int*)(ws + BAR_OFF + 8448);
  f16* WX0p = (f16*)(ws + WX0_OFF);
  f16* WH0p = (f16*)(ws + WH0_OFF);
  f16* WX1p = (f16*)(ws + WX1_OFF);
  f16* WH1p = (f16*)(ws + WH1_OFF);
  f16* XB   = (f16*)(ws + XB_OFF);
  f16* H0   = (f16*)(ws + H0_OFF);
  f16* H1   = (f16*)(ws + H1_OFF);
  float* C0 = (float*)(ws + C0_OFF);
  float* C1 = (float*)(ws + C1_OFF);
  float* P0b = (float*)(ws + P0_OFF);
  float* P1b = (float*)(ws + P1_OFF);

  __shared__ float lds[4][64][49];

  const int tid  = threadIdx.x;
  const int wg   = blockIdx.x;
  const int gtid = wg * TPB + tid;
  const int GSZ  = NWG * TPB;

  // ---------------- prologue: pack weights (rows = [i|g|o] per 16-unit group) ----------------
  for (int idx = gtid; idx < 3072 * 512; idx += GSZ) {
    int r = idx >> 9, c = idx & 511;
    int g = r / 48, w = r - g * 48, gate = w >> 4, j = w & 15;
    int R = g * 16 + j + (gate == 1 ? 2048 : (gate == 2 ? 3072 : 0));
    WX0p[idx] = (f16)Wx0[R * INDIM + c];
  }
  for (int idx = gtid; idx < 3072 * 1024; idx += GSZ) {
    int r = idx >> 10, c = idx & 1023;
    int g = r / 48, w = r - g * 48, gate = w >> 4, j = w & 15;
    int R = g * 16 + j + (gate == 1 ? 2048 : (gate == 2 ? 3072 : 0));
    WH0p[idx] = (f16)Wh0[R * HDIM + c];
    WX1p[idx] = (f16)Wx1[R * HDIM + c];
    WH1p[idx] = (f16)Wh1[R * HDIM + c];
  }
  for (int idx = gtid; idx < T_STEPS * NB * INDIM; idx += GSZ) {
    int t = idx >> 15, rem = idx & 32767;
    int n = rem >> 9, i = rem & 511;
    XB[idx] = (f16)x[(size_t)n * (T_STEPS * INDIM) + t * INDIM + i];
  }

  int ep = 1;
  gbar2(subs, master, flag, wg, ep);

  // ---------------- persistent 4-group pipeline ----------------
  const int grp  = wg >> 6;      // 0=P0, 1=L0, 2=P1, 3=L1
  const int ug   = wg & 63;      // 16-unit group
  const int lane = tid & 63;
  const int wv   = tid >> 6;
  const int quad = lane >> 4;
  const int lr   = lane & 15;

  const f16* Wp; int K;
  switch (grp) {
    case 0:  Wp = WX0p; K = 512;  break;
    case 1:  Wp = WH0p; K = 1024; break;
    case 2:  Wp = WX1p; K = 1024; break;
    default: Wp = WH1p; K = 1024; break;
  }
  const int Kq  = K >> 2;
  const int ash = (grp == 0) ? 9 : 10;
  const f16* w0 = Wp + (size_t)(ug * 48 +  0 + lr) * K + wv * Kq + quad * 8;
  const f16* w1 = Wp + (size_t)(ug * 48 + 16 + lr) * K + wv * Kq + quad * 8;
  const f16* w2 = Wp + (size_t)(ug * 48 + 32 + lr) * K + wv * Kq + quad * 8;

  const float* bb = (grp == 1) ? b0 : b1;
  const float* wc = (grp == 1) ? Wc0 : Wc1;
  float* cst = (grp == 1) ? C0 : C1;

  for (int s = 0; s < NSTAGES; ++s) {
    const int t = s - grp;                 // pipeline offset = group index
    const bool active = (t >= 0) && (t < T_STEPS);
    if (active) {
      const f16* Abase;
      if (grp == 0)      Abase = XB + (size_t)t * NB * INDIM;         // x_t
      else if (grp == 1) Abase = H0 + (size_t)t * NB * HDIM;          // h0_{t-1}
      else if (grp == 2) Abase = H0 + (size_t)(t + 1) * NB * HDIM;    // h0_t
      else               Abase = H1 + (size_t)((t + 1) & 1) * NB * HDIM; // h1_{t-1}

      f32x4 acc[4][3];
#pragma unroll
      for (int mt = 0; mt < 4; ++mt)
#pragma unroll
        for (int nt = 0; nt < 3; ++nt)
          acc[mt][nt] = (f32x4){0.f, 0.f, 0.f, 0.f};

      const f16* Aw = Abase + wv * Kq + quad * 8;
      if (grp == 0) gemm48<4>(Aw, 9,  w0, w1, w2, lr, acc);
      else          gemm48<8>(Aw, 10, w0, w1, w2, lr, acc);

      // cross-wave K-partial reduce via LDS
#pragma unroll
      for (int mt = 0; mt < 4; ++mt)
#pragma unroll
        for (int nt = 0; nt < 3; ++nt)
#pragma unroll
          for (int r = 0; r < 4; ++r)
            lds[wv][mt * 16 + quad * 4 + r][nt * 16 + lr] = acc[mt][nt][r];
      __syncthreads();

      if ((grp & 1) == 0) {
        // P-group epilogue: store 64x48 fp32 tile to ring (transposed [col][m])
        float* Pb = (grp == 0 ? P0b : P1b) + (size_t)(t & 1) * 3072 * NB;
#pragma unroll
        for (int rep = 0; rep < 12; ++rep) {
          int idx = rep * TPB + tid;
          int m = idx & 63, col = idx >> 6;
          float v = lds[0][m][col] + lds[1][m][col] + lds[2][m][col] + lds[3][m][col];
          Pb[(ug * 48 + col) * NB + m] = v;
        }
      } else {
        // L-group epilogue: gates -> nonlinear -> h, c
        const float* Pb = (grp == 1 ? P0b : P1b) + (size_t)(t & 1) * 3072 * NB;
#pragma unroll
        for (int rep = 0; rep < 4; ++rep) {
          int idx = rep * TPB + tid;
          int m = idx & 63, j = idx >> 6;
          int u = ug * 16 + j;
          float gi = lds[0][m][j]      + lds[1][m][j]      + lds[2][m][j]      + lds[3][m][j]
                   + Pb[(ug * 48 + j) * NB + m]      + bb[u];
          float gg = lds[0][m][16 + j] + lds[1][m][16 + j] + lds[2][m][16 + j] + lds[3][m][16 + j]
                   + Pb[(ug * 48 + 16 + j) * NB + m] + bb[2048 + u];
          float go = lds[0][m][32 + j] + lds[1][m][32 + j] + lds[2][m][32 + j] + lds[3][m][32 + j]
                   + Pb[(ug * 48 + 32 + j) * NB + m] + bb[3072 + u];
          float cold = cst[m * HDIM + u];
          float iv = sigm(gi + wc[u] * cold);            // i peephole Wc[0]
          float gv = tanhfast(gg);                       // g
          float ov = sigm(go + wc[2048 + u] * cold);     // o peephole Wc[2]
          float cn = gv * (cold + iv);     // faithful: ct = g*c + i*g
          float hv = ov * tanhfast(cold);  // faithful: uses OLD cell state
          cst[m * HDIM + u] = cn;
          if (grp == 1) {
            H0[(size_t)(t + 1) * NB * HDIM + m * HDIM + u] = (f16)hv;
          } else {
            H1[(size_t)(t & 1) * NB * HDIM + m * HDIM + u] = (f16)hv;
            out[(size_t)m * (T_STEPS * HDIM) + (size_t)t * HDIM + u] = hv;
            if (t == T_STEPS - 1) {
              out[(size_t)NB * T_STEPS * HDIM + m * HDIM + u] = hv;             // final h1
              out[(size_t)NB * T_STEPS * HDIM + NB * HDIM + m * HDIM + u] = cn; // final c1
            }
          }
        }
      }
    }
    if (s < NSTAGES - 1) gbar2(subs, master, flag, wg, ++ep);
  }
}

extern "C" void kernel_launch(void* const* d_in, const int* in_sizes, int n_in,
                              void* d_out, int out_size, void* d_ws, size_t ws_size,
                              hipStream_t stream) {
  const float* x   = (const float*)d_in[0];
  const float* Wx0 = (const float*)d_in[1];
  const float* Wh0 = (const float*)d_in[2];
  const float* b0  = (const float*)d_in[3];
  const float* Wc0 = (const float*)d_in[4];
  const float* Wx1 = (const float*)d_in[5];
  const float* Wh1 = (const float*)d_in[6];
  const float* b1  = (const float*)d_in[7];
  const float* Wc1 = (const float*)d_in[8];
  char* ws = (char*)d_ws;

  // ws is re-poisoned before every timed launch: re-init barrier + state.
  hipMemsetAsync(ws + BAR_OFF, 0, 16384, stream);               // barrier lines
  hipMemsetAsync(ws + H0_OFF, 0, NB * HDIM * 2, stream);        // h0_{-1} = 0 (slot 0)
  hipMemsetAsync(ws + H1_OFF, 0, 2 * NB * HDIM * 2, stream);    // h1 ring = 0
  hipMemsetAsync(ws + C0_OFF, 0, 2 * NB * HDIM * 4, stream);    // c0, c1 = 0 (contiguous)

  hipLaunchKernelGGL(lstm_pers, dim3(NWG), dim3(TPB), 0, stream,
                     x, Wx0, Wh0, b0, Wc0, Wx1, Wh1, b1, Wc1,
                     (float*)d_out, ws);
}

// Round 3
// 4002.235 us; speedup vs baseline: 1.6890x; 1.6061x over previous
//
#include <hip/hip_runtime.h>
#include <stdint.h>

// Fence-free dataflow-pipelined persistent LSTM, MI355X.
// 4 groups x 64 WGs (256 total, 1 WG/CU):
//   P0: G0(t) = x_t @ Wx0p^T          (K=512)  -> P0 ring (free-running, ring credit 8)
//   L0: h0_t  = eps(P0 + h0_{t-1} @ Wh0p^T)    (K=1024)
//   P1: G1(t) = h0_t @ Wx1p^T         (K=1024) -> P1 ring
//   L1: h1_t  = eps(P1 + h1_{t-1} @ Wh1p^T)    (K=1024) -> out
// Sync: per-(group,step) arrival counters, RELAXED agent atomics ONLY
// (no acquire/release fences -> no buffer_wbl2/buffer_inv -> L2 stays warm).
// Visibility: cross-WG data written via sc1 write-through atomic stores,
// drained (s_waitcnt 0 + barrier) before arrival; consumers read h/x/weights
// with NORMAL cached loads at unique never-touched addresses (cold miss -> L3),
// P rings (reused addresses) read via sc1 atomic loads.
// f-gate dead code (reference quirk) -> [i|g|o] = 48 gate rows per 16 units.

#define T_STEPS 256
#define HDIM    1024
#define NB      64
#define INDIM   512
#define NWG     256
#define TPB     256
#define PRING   8

typedef _Float16 f16;
typedef __attribute__((ext_vector_type(8))) _Float16 f16x8;
typedef __attribute__((ext_vector_type(4))) float    f32x4;

// ws byte offsets
#define CNT_OFF 0            // proCnt @0; 4 arrays of 257 counters, 64B stride
#define WX0_OFF 81920        // f16 [3072][512]
#define WH0_OFF 3227648      // f16 [3072][1024]
#define WX1_OFF 9519104      // f16 [3072][1024]
#define WH1_OFF 15810560     // f16 [3072][1024]
#define XB_OFF  22102016     // f16 [256][64][512]
#define H0_OFF  38879232     // f16 [257][64][1024]  slot t = h0_{t-1}
#define H1_OFF  72564736     // f16 [257][64][1024]  slot t = h1_{t-1}
#define C0_OFF  106250240    // f32 [64][1024]
#define C1_OFF  106512384    // f32 [64][1024]
#define P0_OFF  106774528    // f32 [8][3072][64]
#define P1_OFF  113065984    // f32 [8][3072][64]

__device__ __forceinline__ float sigm(float x)     { return 1.0f / (1.0f + __expf(-x)); }
__device__ __forceinline__ float tanhfast(float x) { float e = __expf(2.0f * x); return 1.0f - 2.0f / (e + 1.0f); }

__device__ __forceinline__ void arrive(int* c) {
  __hip_atomic_fetch_add(c, 1, __ATOMIC_RELAXED, __HIP_MEMORY_SCOPE_AGENT);
}
__device__ __forceinline__ void wait_ge(int* c, int v) {
  while (__hip_atomic_load(c, __ATOMIC_RELAXED, __HIP_MEMORY_SCOPE_AGENT) < v)
    __builtin_amdgcn_s_sleep(1);
  __atomic_signal_fence(__ATOMIC_ACQUIRE);
}
__device__ __forceinline__ void st2h(f16* p, float a, float b) {
  union { f16 h[2]; uint32_t u; } cc; cc.h[0] = (f16)a; cc.h[1] = (f16)b;
  __hip_atomic_store((uint32_t*)p, cc.u, __ATOMIC_RELAXED, __HIP_MEMORY_SCOPE_AGENT);
}
__device__ __forceinline__ void stf(float* p, float v) {
  __hip_atomic_store(p, v, __ATOMIC_RELAXED, __HIP_MEMORY_SCOPE_AGENT);
}
__device__ __forceinline__ float ldf(const float* p) {
  return __hip_atomic_load(p, __ATOMIC_RELAXED, __HIP_MEMORY_SCOPE_AGENT);
}

template<int NIT>
__device__ __forceinline__ void gemm48(const f16* __restrict__ Aw, int ash,
                                       const f16* __restrict__ w0,
                                       const f16* __restrict__ w1,
                                       const f16* __restrict__ w2,
                                       int lr, f32x4 (&acc)[4][3]) {
  const f16* a0 = Aw + ((size_t)(lr +  0) << ash);
  const f16* a1 = Aw + ((size_t)(lr + 16) << ash);
  const f16* a2 = Aw + ((size_t)(lr + 32) << ash);
  const f16* a3 = Aw + ((size_t)(lr + 48) << ash);
#pragma unroll
  for (int it = 0; it < NIT; ++it) {
    const int kk = it * 32;
    f16x8 A0 = *(const f16x8*)(a0 + kk);
    f16x8 A1 = *(const f16x8*)(a1 + kk);
    f16x8 A2 = *(const f16x8*)(a2 + kk);
    f16x8 A3 = *(const f16x8*)(a3 + kk);
    f16x8 B0 = *(const f16x8*)(w0 + kk);
    f16x8 B1 = *(const f16x8*)(w1 + kk);
    f16x8 B2 = *(const f16x8*)(w2 + kk);
    acc[0][0] = __builtin_amdgcn_mfma_f32_16x16x32_f16(A0, B0, acc[0][0], 0, 0, 0);
    acc[0][1] = __builtin_amdgcn_mfma_f32_16x16x32_f16(A0, B1, acc[0][1], 0, 0, 0);
    acc[0][2] = __builtin_amdgcn_mfma_f32_16x16x32_f16(A0, B2, acc[0][2], 0, 0, 0);
    acc[1][0] = __builtin_amdgcn_mfma_f32_16x16x32_f16(A1, B0, acc[1][0], 0, 0, 0);
    acc[1][1] = __builtin_amdgcn_mfma_f32_16x16x32_f16(A1, B1, acc[1][1], 0, 0, 0);
    acc[1][2] = __builtin_amdgcn_mfma_f32_16x16x32_f16(A1, B2, acc[1][2], 0, 0, 0);
    acc[2][0] = __builtin_amdgcn_mfma_f32_16x16x32_f16(A2, B0, acc[2][0], 0, 0, 0);
    acc[2][1] = __builtin_amdgcn_mfma_f32_16x16x32_f16(A2, B1, acc[2][1], 0, 0, 0);
    acc[2][2] = __builtin_amdgcn_mfma_f32_16x16x32_f16(A2, B2, acc[2][2], 0, 0, 0);
    acc[3][0] = __builtin_amdgcn_mfma_f32_16x16x32_f16(A3, B0, acc[3][0], 0, 0, 0);
    acc[3][1] = __builtin_amdgcn_mfma_f32_16x16x32_f16(A3, B1, acc[3][1], 0, 0, 0);
    acc[3][2] = __builtin_amdgcn_mfma_f32_16x16x32_f16(A3, B2, acc[3][2], 0, 0, 0);
  }
}

__global__ __launch_bounds__(TPB) void lstm_pers(
    const float* __restrict__ x,
    const float* __restrict__ Wx0, const float* __restrict__ Wh0,
    const float* __restrict__ b0,  const float* __restrict__ Wc0,
    const float* __restrict__ Wx1, const float* __restrict__ Wh1,
    const float* __restrict__ b1,  const float* __restrict__ Wc1,
    float* __restrict__ out, char* __restrict__ ws)
{
  int* cbase = (int*)(ws + CNT_OFF);
  int* proCnt = cbase;
  auto CNT = [&](int g, int t) { return cbase + 16 + ((g * 257 + t) << 4); };

  f16* WX0p = (f16*)(ws + WX0_OFF);
  f16* WH0p = (f16*)(ws + WH0_OFF);
  f16* WX1p = (f16*)(ws + WX1_OFF);
  f16* WH1p = (f16*)(ws + WH1_OFF);
  f16* XB   = (f16*)(ws + XB_OFF);
  f16* H0   = (f16*)(ws + H0_OFF);
  f16* H1   = (f16*)(ws + H1_OFF);
  float* C0 = (float*)(ws + C0_OFF);
  float* C1 = (float*)(ws + C1_OFF);
  float* P0b = (float*)(ws + P0_OFF);
  float* P1b = (float*)(ws + P1_OFF);

  __shared__ float lds[4][64][49];

  const int tid  = threadIdx.x;
  const int wg   = blockIdx.x;
  const int gtid = wg * TPB + tid;
  const int GSZ  = NWG * TPB;

  // ---------------- prologue: pack weights/x as f16 via sc1 write-through pair stores ----------------
  for (int idx = gtid; idx < 3072 * 256; idx += GSZ) {           // Wx0 pack
    int r = idx >> 8, c2 = (idx & 255) << 1;
    int g = r / 48, w = r - g * 48, gate = w >> 4, j = w & 15;
    int R = g * 16 + j + (gate == 1 ? 2048 : (gate == 2 ? 3072 : 0));
    st2h(&WX0p[idx << 1], Wx0[R * INDIM + c2], Wx0[R * INDIM + c2 + 1]);
  }
  for (int idx = gtid; idx < 3072 * 512; idx += GSZ) {           // Wh0/Wx1/Wh1 pack
    int r = idx >> 9, c2 = (idx & 511) << 1;
    int g = r / 48, w = r - g * 48, gate = w >> 4, j = w & 15;
    int R = g * 16 + j + (gate == 1 ? 2048 : (gate == 2 ? 3072 : 0));
    st2h(&WH0p[idx << 1], Wh0[R * HDIM + c2], Wh0[R * HDIM + c2 + 1]);
    st2h(&WX1p[idx << 1], Wx1[R * HDIM + c2], Wx1[R * HDIM + c2 + 1]);
    st2h(&WH1p[idx << 1], Wh1[R * HDIM + c2], Wh1[R * HDIM + c2 + 1]);
  }
  for (int idx = gtid; idx < T_STEPS * NB * 256; idx += GSZ) {   // x pack, time-major
    int t = idx >> 14, n = (idx >> 8) & 63, i2 = (idx & 255) << 1;
    const float* src = x + (size_t)n * (T_STEPS * INDIM) + (size_t)t * INDIM + i2;
    st2h(&XB[(size_t)idx << 1], src[0], src[1]);
  }

  // light grid barrier (no cache fences; all shared data went through sc1)
  __builtin_amdgcn_s_waitcnt(0);
  __syncthreads();
  if (tid == 0) { arrive(proCnt); wait_ge(proCnt, NWG); }
  __syncthreads();

  // ---------------- persistent 4-group dataflow pipeline ----------------
  const int grp  = wg >> 6;      // 0=P0, 1=L0, 2=P1, 3=L1
  const int ug   = wg & 63;
  const int lane = tid & 63;
  const int wv   = tid >> 6;
  const int quad = lane >> 4;
  const int lr   = lane & 15;

  const f16* Wp; int K;
  switch (grp) {
    case 0:  Wp = WX0p; K = 512;  break;
    case 1:  Wp = WH0p; K = 1024; break;
    case 2:  Wp = WX1p; K = 1024; break;
    default: Wp = WH1p; K = 1024; break;
  }
  const int Kq  = K >> 2;
  const f16* w0 = Wp + (size_t)(ug * 48 +  0 + lr) * K + wv * Kq + quad * 8;
  const f16* w1 = Wp + (size_t)(ug * 48 + 16 + lr) * K + wv * Kq + quad * 8;
  const f16* w2 = Wp + (size_t)(ug * 48 + 32 + lr) * K + wv * Kq + quad * 8;

  const float* bb = (grp == 1) ? b0 : b1;
  const float* wc = (grp == 1) ? Wc0 : Wc1;
  float* cst = (grp == 1) ? C0 : C1;

  for (int t = 0; t < T_STEPS; ++t) {
    // ---- wait for inputs / ring credits (thread 0 polls, no fences) ----
    if (tid == 0) {
      if (grp == 0)      { if (t >= PRING) wait_ge(CNT(1, t - PRING), 64); }
      else if (grp == 1) { wait_ge(CNT(0, t), 64); if (t) wait_ge(CNT(1, t - 1), 64); }
      else if (grp == 2) { wait_ge(CNT(1, t), 64); if (t >= PRING) wait_ge(CNT(3, t - PRING), 64); }
      else               { wait_ge(CNT(2, t), 64); if (t) wait_ge(CNT(3, t - 1), 64); }
    }
    __syncthreads();

    const f16* Abase;
    if (grp == 0)      Abase = XB + (size_t)t * NB * INDIM;          // x_t
    else if (grp == 1) Abase = H0 + (size_t)t * NB * HDIM;           // h0_{t-1}
    else if (grp == 2) Abase = H0 + (size_t)(t + 1) * NB * HDIM;     // h0_t
    else               Abase = H1 + (size_t)t * NB * HDIM;           // h1_{t-1}

    f32x4 acc[4][3];
#pragma unroll
    for (int mt = 0; mt < 4; ++mt)
#pragma unroll
      for (int nt = 0; nt < 3; ++nt)
        acc[mt][nt] = (f32x4){0.f, 0.f, 0.f, 0.f};

    const f16* Aw = Abase + wv * Kq + quad * 8;
    if (grp == 0) gemm48<4>(Aw, 9,  w0, w1, w2, lr, acc);
    else          gemm48<8>(Aw, 10, w0, w1, w2, lr, acc);

    // cross-wave K-partial reduce via LDS
#pragma unroll
    for (int mt = 0; mt < 4; ++mt)
#pragma unroll
      for (int nt = 0; nt < 3; ++nt)
#pragma unroll
        for (int r = 0; r < 4; ++r)
          lds[wv][mt * 16 + quad * 4 + r][nt * 16 + lr] = acc[mt][nt][r];
    __syncthreads();

    if ((grp & 1) == 0) {
      // P-group epilogue: 64x48 fp32 tile -> ring via sc1 stores
      float* Pb = (grp == 0 ? P0b : P1b) + (size_t)(t & (PRING - 1)) * 3072 * NB;
#pragma unroll
      for (int rep = 0; rep < 12; ++rep) {
        int idx = rep * TPB + tid;
        int m = idx & 63, col = idx >> 6;
        float v = lds[0][m][col] + lds[1][m][col] + lds[2][m][col] + lds[3][m][col];
        stf(&Pb[(ug * 48 + col) * NB + m], v);
      }
    } else {
      // L-group epilogue: gates -> nonlinear -> h (sc1 pair store), c (local)
      const float* Pb = (grp == 1 ? P0b : P1b) + (size_t)(t & (PRING - 1)) * 3072 * NB;
      f16* Hdst = (grp == 1 ? H0 : H1) + (size_t)(t + 1) * NB * HDIM;
#pragma unroll
      for (int rep = 0; rep < 2; ++rep) {
        int idx2 = rep * TPB + tid;
        int m = idx2 >> 3, jp = (idx2 & 7) << 1;
        float hv2[2], cn2[2];
#pragma unroll
        for (int q = 0; q < 2; ++q) {
          int j = jp + q;
          int u = ug * 16 + j;
          float gi = lds[0][m][j]      + lds[1][m][j]      + lds[2][m][j]      + lds[3][m][j]
                   + ldf(&Pb[(ug * 48 + j) * NB + m])      + bb[u];
          float gg = lds[0][m][16 + j] + lds[1][m][16 + j] + lds[2][m][16 + j] + lds[3][m][16 + j]
                   + ldf(&Pb[(ug * 48 + 16 + j) * NB + m]) + bb[2048 + u];
          float go = lds[0][m][32 + j] + lds[1][m][32 + j] + lds[2][m][32 + j] + lds[3][m][32 + j]
                   + ldf(&Pb[(ug * 48 + 32 + j) * NB + m]) + bb[3072 + u];
          float cold = cst[m * HDIM + u];
          float iv = sigm(gi + wc[u] * cold);            // i peephole Wc[0]
          float gv = tanhfast(gg);                       // g
          float ov = sigm(go + wc[2048 + u] * cold);     // o peephole Wc[2]
          cn2[q] = gv * (cold + iv);     // faithful: ct = g*c + i*g
          hv2[q] = ov * tanhfast(cold);  // faithful: uses OLD cell state
          cst[m * HDIM + u] = cn2[q];
        }
        int u0 = ug * 16 + jp;
        st2h(&Hdst[m * HDIM + u0], hv2[0], hv2[1]);
        if (grp == 3) {
          float2* o2 = (float2*)&out[(size_t)m * (T_STEPS * HDIM) + (size_t)t * HDIM + u0];
          *o2 = make_float2(hv2[0], hv2[1]);
          if (t == T_STEPS - 1) {
            float2* hf = (float2*)&out[(size_t)NB * T_STEPS * HDIM + m * HDIM + u0];
            *hf = make_float2(hv2[0], hv2[1]);
            float2* cf = (float2*)&out[(size_t)NB * T_STEPS * HDIM + NB * HDIM + m * HDIM + u0];
            *cf = make_float2(cn2[0], cn2[1]);
          }
        }
      }
    }

    // drain sc1 data stores, then signal arrival
    __builtin_amdgcn_s_waitcnt(0);
    __syncthreads();
    if (tid == 0) arrive(CNT(grp, t));
  }
}

extern "C" void kernel_launch(void* const* d_in, const int* in_sizes, int n_in,
                              void* d_out, int out_size, void* d_ws, size_t ws_size,
                              hipStream_t stream) {
  const float* x   = (const float*)d_in[0];
  const float* Wx0 = (const float*)d_in[1];
  const float* Wh0 = (const float*)d_in[2];
  const float* b0  = (const float*)d_in[3];
  const float* Wc0 = (const float*)d_in[4];
  const float* Wx1 = (const float*)d_in[5];
  const float* Wh1 = (const float*)d_in[6];
  const float* b1  = (const float*)d_in[7];
  const float* Wc1 = (const float*)d_in[8];
  char* ws = (char*)d_ws;

  // ws re-poisoned before each timed launch: zero counters + initial state
  hipMemsetAsync(ws + CNT_OFF, 0, 81920, stream);              // all counters
  hipMemsetAsync(ws + H0_OFF, 0, NB * HDIM * 2, stream);       // h0_{-1} = 0 (slot 0)
  hipMemsetAsync(ws + H1_OFF, 0, NB * HDIM * 2, stream);       // h1_{-1} = 0 (slot 0)
  hipMemsetAsync(ws + C0_OFF, 0, 2 * NB * HDIM * 4, stream);   // c0, c1 = 0 (contiguous)

  hipLaunchKernelGGL(lstm_pers, dim3(NWG), dim3(TPB), 0, stream,
                     x, Wx0, Wh0, b0, Wc0, Wx1, Wh1, b1, Wc1,
                     (float*)d_out, ws);
}